// Round 1
// baseline (121.095 us; speedup 1.0000x reference)
//
#include <hip/hip_runtime.h>
#include <math.h>

#define H 1024
#define V 128000
#define G3H 3072   // 3*H

// ws layout (floats): [0..3071]=gi, [3072..6143]=gh, [6144]=gmax, [6145]=log(sumexp)
#define WS_GI   0
#define WS_GH   G3H
#define WS_GMAX (2*G3H)
#define WS_LSE  (2*G3H + 1)

// -------- Kernel A: gi = W_ih @ relu(emb[id]) + b_ih ; gh = W_hh @ h0 + b_hh
// One wave (64 lanes) per output row. Rows [0,3072) -> gi, [3072,6144) -> gh.
__global__ __launch_bounds__(256) void gates_matvec(
    const int* __restrict__ ids, const float* __restrict__ hidden,
    const float* __restrict__ emb,
    const float* __restrict__ W_ih, const float* __restrict__ W_hh,
    const float* __restrict__ b_ih, const float* __restrict__ b_hh,
    float* __restrict__ ws) {
  const int wid  = (blockIdx.x * blockDim.x + threadIdx.x) >> 6;  // global wave id, 0..6143
  const int lane = threadIdx.x & 63;
  const int id   = ids[0];

  const bool isGi = (wid < G3H);
  const int  row  = isGi ? wid : (wid - G3H);

  const float4* w = (const float4*)((isGi ? W_ih : W_hh) + (size_t)row * H);
  const float4* v = (const float4*)(isGi ? (emb + (size_t)id * H) : hidden);

  float sum = 0.f;
#pragma unroll
  for (int k = 0; k < 4; ++k) {
    float4 wv = w[lane + 64 * k];
    float4 xv = v[lane + 64 * k];
    if (isGi) {  // x = relu(emb row)
      xv.x = fmaxf(xv.x, 0.f); xv.y = fmaxf(xv.y, 0.f);
      xv.z = fmaxf(xv.z, 0.f); xv.w = fmaxf(xv.w, 0.f);
    }
    sum = fmaf(wv.x, xv.x, sum);
    sum = fmaf(wv.y, xv.y, sum);
    sum = fmaf(wv.z, xv.z, sum);
    sum = fmaf(wv.w, xv.w, sum);
  }
#pragma unroll
  for (int off = 32; off > 0; off >>= 1) sum += __shfl_down(sum, off);

  if (lane == 0) {
    const float b = isGi ? b_ih[row] : b_hh[row];
    ws[wid] = sum + b;   // ws[row] = gi[row]; ws[3072+row] = gh[row]
  }
}

// -------- Kernel C: GRU gate fusion -> h1 written to d_out[V + i]
__global__ __launch_bounds__(256) void gru_gate(
    const float* __restrict__ hidden, const float* __restrict__ ws,
    float* __restrict__ d_out) {
  const int i = blockIdx.x * blockDim.x + threadIdx.x;  // 0..1023
  const float* gi = ws + WS_GI;
  const float* gh = ws + WS_GH;
  const float r = 1.f / (1.f + expf(-(gi[i]           + gh[i])));
  const float z = 1.f / (1.f + expf(-(gi[H + i]       + gh[H + i])));
  const float n = tanhf(gi[2 * H + i] + r * gh[2 * H + i]);
  const float h0 = hidden[i];
  d_out[V + i] = (1.f - z) * n + z * h0;
}

// -------- Kernel B1: logits[v] = W_out[v,:] @ h1 + b_out[v], into d_out[0..V)
// One wave per row, 4 rows per block. h1 staged in LDS.
__global__ __launch_bounds__(256) void logits_matvec(
    const float* __restrict__ W_out, const float* __restrict__ b_out,
    float* __restrict__ d_out) {
  __shared__ float4 h1s[256];
  h1s[threadIdx.x] = ((const float4*)(d_out + V))[threadIdx.x];
  __syncthreads();

  const int lane = threadIdx.x & 63;
  const int row  = blockIdx.x * 4 + (threadIdx.x >> 6);
  const float4* w = (const float4*)(W_out + (size_t)row * H);

  float sum = 0.f;
#pragma unroll
  for (int k = 0; k < 4; ++k) {
    const float4 wv = w[lane + 64 * k];
    const float4 xv = h1s[lane + 64 * k];
    sum = fmaf(wv.x, xv.x, sum);
    sum = fmaf(wv.y, xv.y, sum);
    sum = fmaf(wv.z, xv.z, sum);
    sum = fmaf(wv.w, xv.w, sum);
  }
#pragma unroll
  for (int off = 32; off > 0; off >>= 1) sum += __shfl_down(sum, off);

  if (lane == 0) d_out[row] = sum + b_out[row];
}

// -------- Kernel B2: single-block log-sum-exp reduce over d_out[0..V)
__global__ __launch_bounds__(1024) void lse_reduce(
    const float* __restrict__ logits, float* __restrict__ ws) {
  __shared__ float red[1024];
  const int t = threadIdx.x;
  const float4* l4 = (const float4*)logits;  // V/4 = 32000 float4s

  float m = -INFINITY;
  for (int i = t; i < V / 4; i += 1024) {
    const float4 v = l4[i];
    m = fmaxf(m, fmaxf(fmaxf(v.x, v.y), fmaxf(v.z, v.w)));
  }
  red[t] = m;
  __syncthreads();
  for (int s = 512; s > 0; s >>= 1) {
    if (t < s) red[t] = fmaxf(red[t], red[t + s]);
    __syncthreads();
  }
  const float gmax = red[0];
  __syncthreads();

  float sum = 0.f;
  for (int i = t; i < V / 4; i += 1024) {
    const float4 v = l4[i];
    sum += expf(v.x - gmax) + expf(v.y - gmax) + expf(v.z - gmax) + expf(v.w - gmax);
  }
  red[t] = sum;
  __syncthreads();
  for (int s = 512; s > 0; s >>= 1) {
    if (t < s) red[t] += red[t + s];
    __syncthreads();
  }
  if (t == 0) {
    ws[WS_GMAX] = gmax;
    ws[WS_LSE]  = logf(red[0]);
  }
}

// -------- Kernel B3: in-place logp[v] = logits[v] - gmax - lse
__global__ __launch_bounds__(256) void logp_write(
    float* __restrict__ d_out, const float* __restrict__ ws) {
  const int v = blockIdx.x * blockDim.x + threadIdx.x;  // exactly covers V
  const float gmax = ws[WS_GMAX];
  const float lse  = ws[WS_LSE];
  d_out[v] = d_out[v] - gmax - lse;
}

extern "C" void kernel_launch(void* const* d_in, const int* in_sizes, int n_in,
                              void* d_out, int out_size, void* d_ws, size_t ws_size,
                              hipStream_t stream) {
  const int*   ids    = (const int*)d_in[0];
  const float* hidden = (const float*)d_in[1];
  const float* emb    = (const float*)d_in[2];
  const float* W_ih   = (const float*)d_in[3];
  const float* W_hh   = (const float*)d_in[4];
  const float* b_ih   = (const float*)d_in[5];
  const float* b_hh   = (const float*)d_in[6];
  const float* W_out  = (const float*)d_in[7];
  const float* b_out  = (const float*)d_in[8];
  float* out = (float*)d_out;
  float* ws  = (float*)d_ws;

  // A: 6144 rows, 1 wave each, 4 waves/block -> 1536 blocks
  gates_matvec<<<1536, 256, 0, stream>>>(ids, hidden, emb, W_ih, W_hh, b_ih, b_hh, ws);
  // C: 1024 gate elements
  gru_gate<<<4, 256, 0, stream>>>(hidden, ws, out);
  // B1: 128000 rows, 1 wave each, 4 rows/block -> 32000 blocks
  logits_matvec<<<V / 4, 256, 0, stream>>>(W_out, b_out, out);
  // B2: one block LSE reduce
  lse_reduce<<<1, 1024, 0, stream>>>(out, ws);
  // B3: normalize in place
  logp_write<<<V / 256, 256, 0, stream>>>(out, ws);
}